// Round 8
// baseline (498.724 us; speedup 1.0000x reference)
//
#include <hip/hip_runtime.h>
#include <math.h>

#define BB 2
#define HH 8
#define SS 2048
#define CC 64
#define CIN 512
#define DDIM 512           // H*C
#define MM (BB*SS)         // 4096
#define KCHUNK 64
#define NCHUNK (SS / KCHUNK) // 32 chunks, full key domain per wave

#define LOG2E 1.4426950408889634f
#define SHIFT2 (16.0f * LOG2E)   // softmax shift in log2 domain

using short8  = __attribute__((ext_vector_type(8))) short;
using float4v = __attribute__((ext_vector_type(4))) float;

__device__ __forceinline__ unsigned short tob(float f) {
    unsigned u = __float_as_uint(f);
    unsigned r = (u + 0x7fffu + ((u >> 16) & 1u)) >> 16;
    return (unsigned short)r;
}
__device__ __forceinline__ float fromb(unsigned short u) {
    return __uint_as_float(((unsigned)u) << 16);
}

// ---------------------------------------------------------------- convert ---
__global__ __launch_bounds__(256) void convert_all(
    const float* __restrict__ x,
    const float* __restrict__ wq, const float* __restrict__ wk,
    const float* __restrict__ wv, const float* __restrict__ wg,
    const float* __restrict__ wo,
    unsigned short* __restrict__ xb,
    unsigned short* __restrict__ wqb, unsigned short* __restrict__ wkb,
    unsigned short* __restrict__ wvb, unsigned short* __restrict__ wgb,
    unsigned short* __restrict__ wob)
{
    const int NX4 = MM * CIN / 4;       // 524288
    int i = blockIdx.x * blockDim.x + threadIdx.x;
    const float* src; unsigned short* dst; float scale = 1.0f; int off;
    if (i < NX4) { src = x; dst = xb; off = i; }
    else {
        int j = i - NX4;
        int seg = j >> 16;              // 65536 float4 per 512x512 weight
        off = j & 65535;
        // Wq pre-scaled by (1/8)*log2(e) so QK^T scores land in log2 units.
        if      (seg == 0) { src = wq; dst = wqb; scale = 0.125f * LOG2E; }
        else if (seg == 1) { src = wk; dst = wkb; }
        else if (seg == 2) { src = wv; dst = wvb; }
        else if (seg == 3) { src = wg; dst = wgb; }
        else               { src = wo; dst = wob; }
    }
    float4 v = ((const float4*)src)[off];
    ushort4 o;
    o.x = tob(v.x * scale); o.y = tob(v.y * scale);
    o.z = tob(v.z * scale); o.w = tob(v.w * scale);
    ((ushort4*)dst)[off] = o;
}

// ------------------------------------------------------------- projection ---
// mode (blockIdx.z): 0 Q->[B,H,S,C] (pre-scaled, log2-domain), 1 K->[B,H,S,C],
// 2 V->[B,H,C,S] (LDS transpose), 3 G=sigmoid(P+bg)->[MM][512]
__global__ __launch_bounds__(256) void proj_gemm(
    const unsigned short* __restrict__ X,
    const unsigned short* __restrict__ Wq,
    const unsigned short* __restrict__ Wk,
    const unsigned short* __restrict__ Wv,
    const unsigned short* __restrict__ Wg,
    const float* __restrict__ bg,
    unsigned short* __restrict__ Qd,
    unsigned short* __restrict__ Kd,
    unsigned short* __restrict__ Vd,
    unsigned short* __restrict__ Gd)
{
    __shared__ __align__(16) unsigned short At[64][72];
    __shared__ __align__(16) unsigned short Bt[64][72];

    int mode = blockIdx.z;
    const unsigned short* W = (mode == 0) ? Wq : (mode == 1) ? Wk : (mode == 2) ? Wv : Wg;

    int m0 = blockIdx.y * 64;
    int n0 = blockIdx.x * 64;
    int tid = threadIdx.x;
    int w = tid >> 6, lane = tid & 63;
    int quad = lane >> 4, l16 = lane & 15;
    int wm = w & 1, wn = w >> 1;

    float4v acc[2][2];
    for (int a = 0; a < 2; ++a) for (int c = 0; c < 2; ++c) acc[a][c] = (float4v)0.0f;

    for (int kc = 0; kc < CIN; kc += 64) {
        for (int it = 0; it < 2; ++it) {
            int idx = it * 2048 + tid * 8;
            int row = idx >> 6, col = idx & 63;
            *(short8*)&At[row][col] = *(const short8*)&X[(size_t)(m0 + row) * CIN + kc + col];
            *(short8*)&Bt[row][col] = *(const short8*)&W[(size_t)(n0 + row) * CIN + kc + col];
        }
        __syncthreads();
        for (int ks = 0; ks < 2; ++ks) {
            short8 a0 = *(const short8*)&At[wm * 32 + l16][ks * 32 + quad * 8];
            short8 a1 = *(const short8*)&At[wm * 32 + 16 + l16][ks * 32 + quad * 8];
            short8 b0 = *(const short8*)&Bt[wn * 32 + l16][ks * 32 + quad * 8];
            short8 b1 = *(const short8*)&Bt[wn * 32 + 16 + l16][ks * 32 + quad * 8];
            acc[0][0] = __builtin_amdgcn_mfma_f32_16x16x32_bf16(a0, b0, acc[0][0], 0, 0, 0);
            acc[0][1] = __builtin_amdgcn_mfma_f32_16x16x32_bf16(a0, b1, acc[0][1], 0, 0, 0);
            acc[1][0] = __builtin_amdgcn_mfma_f32_16x16x32_bf16(a1, b0, acc[1][0], 0, 0, 0);
            acc[1][1] = __builtin_amdgcn_mfma_f32_16x16x32_bf16(a1, b1, acc[1][1], 0, 0, 0);
        }
        __syncthreads();
    }

    if (mode == 2) {
        for (int a = 0; a < 2; ++a) for (int c = 0; c < 2; ++c)
            for (int r = 0; r < 4; ++r) {
                int ml = wm * 32 + a * 16 + quad * 4 + r;     // s-local
                int nl = wn * 32 + c * 16 + l16;              // c-local
                At[nl][ml] = tob(acc[a][c][r]);
            }
        __syncthreads();
        int bi = m0 >> 11, h = n0 >> 6, s0 = m0 & 2047;
        int crow = tid >> 2, seg = tid & 3;
        unsigned short* dp = Vd + (((size_t)(bi * HH + h) * CC) + crow) * SS + s0 + seg * 16;
        *(short8*)dp       = *(const short8*)&At[crow][seg * 16];
        *(short8*)(dp + 8) = *(const short8*)&At[crow][seg * 16 + 8];
        return;
    }

    for (int a = 0; a < 2; ++a) for (int c = 0; c < 2; ++c)
        for (int r = 0; r < 4; ++r) {
            int gm = m0 + wm * 32 + a * 16 + quad * 4 + r;
            int gn = n0 + wn * 32 + c * 16 + l16;
            float v = acc[a][c][r];
            if (mode <= 1) {
                int bi = gm >> 11, s = gm & 2047, h = gn >> 6, cc = gn & 63;
                unsigned short* d = (mode == 0) ? Qd : Kd;
                d[(((size_t)(bi * HH + h) * SS) + s) * CC + cc] = tob(v);
            } else {
                float g = 1.0f / (1.0f + __expf(-(v + bg[gn])));
                Gd[(size_t)gm * DDIM + gn] = tob(g);
            }
        }
}

// -------------------------------------------------------------- attention ---
// ROUND-8: BARRIER-FREE flash attention. Every prior variant (r0-r7) coupled
// 4 waves x 2 blocks/CU through per-chunk s_barriers around shared-LDS
// staging; the slowest outstanding load gated the whole CU and attn pinned
// at ~2.5 TB/s. The only 6.7 TB/s kernel in evidence (harness fill) has zero
// inter-wave coupling — this version copies that shape:
//  - each WAVE independently processes 16 q-rows over all 2048 keys
//  - bias: per-lane scalar dword loads (pattern bias[quad*4+r][j*16+l16] is
//    directly per-lane addressable), prefetched one 64-key chunk ahead in
//    16+16 NAMED float registers (rule #20: arrays would demote to scratch)
//  - K/V: JIT 16B register loads from global — L2-resident (256 KB/head,
//    reused by 32 blocks of same bh; L2 34 TB/s >> demand)
//  - LDS: only Pt (per-wave P transpose scratch, 9 KB/block), lgkmcnt-only
//  - NO s_barrier, NO asm waitcnt anywhere in the loop
// Fixed-shift softmax (log2): O = (sum 2^(qk*log2e + b*log2e - SHIFT2) v)
//                                 / lsum * g
__global__ __launch_bounds__(256, 2) void attn_kernel(
    const unsigned short* __restrict__ Q,
    const unsigned short* __restrict__ K,
    const unsigned short* __restrict__ V,
    const float* __restrict__ bias,
    const unsigned short* __restrict__ G,
    unsigned short* __restrict__ Om)   // [MM][DDIM] bf16 gated output
{
    __shared__ __align__(16) unsigned short Pt[4][16][72];   // per-wave P

    int qb = blockIdx.x * 64;
    int bh = blockIdx.y;               // b*H + h
    int b = bh >> 3, h = bh & 7;
    int tid = threadIdx.x;
    int w = tid >> 6, lane = tid & 63;
    int quad = lane >> 4, l16 = lane & 15;

    // per-block chunk-phase rotation (fixed-shift softmax is chunk-linear)
    int phase = (blockIdx.x + blockIdx.y) & (NCHUNK - 1);

    const unsigned short* Qbh = Q + (size_t)bh * SS * CC;
    const unsigned short* Kbh = K + (size_t)bh * SS * CC;
    const unsigned short* Vbh = V + (size_t)bh * CC * SS;
    // per-lane bias base: row (qb + w*16 + quad*4), key l16
    const float* brow = bias + (size_t)bh * SS * SS
                      + (size_t)(qb + w * 16 + quad * 4) * SS + l16;

    int qrow = qb + w * 16 + l16;
    short8 aq0 = *(const short8*)&Qbh[(size_t)qrow * CC + quad * 8];
    short8 aq1 = *(const short8*)&Qbh[(size_t)qrow * CC + 32 + quad * 8];

    float lsum[4] = {0.f, 0.f, 0.f, 0.f};
    float4v accO[4];
    for (int jn = 0; jn < 4; ++jn) accO[jn] = (float4v)0.0f;

// 16 named bias scalars per set: S_{j}{r} = bias[row + r][kb + j*16 + lane]
#define DECLB(S) float S##00,S##01,S##02,S##03, S##10,S##11,S##12,S##13, \
                       S##20,S##21,S##22,S##23, S##30,S##31,S##32,S##33
#define LDB(S, kb) do {                                                   \
    S##00 = brow[0*SS+(kb)   ]; S##01 = brow[1*SS+(kb)   ];               \
    S##02 = brow[2*SS+(kb)   ]; S##03 = brow[3*SS+(kb)   ];               \
    S##10 = brow[0*SS+(kb)+16]; S##11 = brow[1*SS+(kb)+16];               \
    S##12 = brow[2*SS+(kb)+16]; S##13 = brow[3*SS+(kb)+16];               \
    S##20 = brow[0*SS+(kb)+32]; S##21 = brow[1*SS+(kb)+32];               \
    S##22 = brow[2*SS+(kb)+32]; S##23 = brow[3*SS+(kb)+32];               \
    S##30 = brow[0*SS+(kb)+48]; S##31 = brow[1*SS+(kb)+48];               \
    S##32 = brow[2*SS+(kb)+48]; S##33 = brow[3*SS+(kb)+48];               \
} while (0)

// softmax row for sub-tile j: p = 2^(fma(bias, log2e, qk - SHIFT2))
#define PEXP(saj, B0, B1, B2, B3, jj) do {                                 \
    float p0 = __builtin_amdgcn_exp2f(fmaf(B0, LOG2E, (saj)[0]));          \
    float p1 = __builtin_amdgcn_exp2f(fmaf(B1, LOG2E, (saj)[1]));          \
    float p2 = __builtin_amdgcn_exp2f(fmaf(B2, LOG2E, (saj)[2]));          \
    float p3 = __builtin_amdgcn_exp2f(fmaf(B3, LOG2E, (saj)[3]));          \
    lsum[0] += p0; lsum[1] += p1; lsum[2] += p2; lsum[3] += p3;            \
    Pt[w][quad * 4 + 0][(jj) * 16 + l16] = tob(p0);                        \
    Pt[w][quad * 4 + 1][(jj) * 16 + l16] = tob(p1);                        \
    Pt[w][quad * 4 + 2][(jj) * 16 + l16] = tob(p2);                        \
    Pt[w][quad * 4 + 3][(jj) * 16 + l16] = tob(p3);                        \
} while (0)

// full 64-key chunk: QK^T (K JIT from L2) + softmax (bias set S) + PV
#define BODY(S, kb) do {                                                   \
    float4v sa0 = (float4v)(-SHIFT2), sa1 = (float4v)(-SHIFT2);            \
    float4v sa2 = (float4v)(-SHIFT2), sa3 = (float4v)(-SHIFT2);            \
    {                                                                      \
        short8 k0, k1;                                                     \
        k0 = *(const short8*)&Kbh[(size_t)((kb) +  0 + l16) * CC + quad * 8];      \
        k1 = *(const short8*)&Kbh[(size_t)((kb) +  0 + l16) * CC + 32 + quad * 8]; \
        sa0 = __builtin_amdgcn_mfma_f32_16x16x32_bf16(aq0, k0, sa0, 0, 0, 0);      \
        sa0 = __builtin_amdgcn_mfma_f32_16x16x32_bf16(aq1, k1, sa0, 0, 0, 0);      \
        k0 = *(const short8*)&Kbh[(size_t)((kb) + 16 + l16) * CC + quad * 8];      \
        k1 = *(const short8*)&Kbh[(size_t)((kb) + 16 + l16) * CC + 32 + quad * 8]; \
        sa1 = __builtin_amdgcn_mfma_f32_16x16x32_bf16(aq0, k0, sa1, 0, 0, 0);      \
        sa1 = __builtin_amdgcn_mfma_f32_16x16x32_bf16(aq1, k1, sa1, 0, 0, 0);      \
        k0 = *(const short8*)&Kbh[(size_t)((kb) + 32 + l16) * CC + quad * 8];      \
        k1 = *(const short8*)&Kbh[(size_t)((kb) + 32 + l16) * CC + 32 + quad * 8]; \
        sa2 = __builtin_amdgcn_mfma_f32_16x16x32_bf16(aq0, k0, sa2, 0, 0, 0);      \
        sa2 = __builtin_amdgcn_mfma_f32_16x16x32_bf16(aq1, k1, sa2, 0, 0, 0);      \
        k0 = *(const short8*)&Kbh[(size_t)((kb) + 48 + l16) * CC + quad * 8];      \
        k1 = *(const short8*)&Kbh[(size_t)((kb) + 48 + l16) * CC + 32 + quad * 8]; \
        sa3 = __builtin_amdgcn_mfma_f32_16x16x32_bf16(aq0, k0, sa3, 0, 0, 0);      \
        sa3 = __builtin_amdgcn_mfma_f32_16x16x32_bf16(aq1, k1, sa3, 0, 0, 0);      \
    }                                                                      \
    PEXP(sa0, S##00, S##01, S##02, S##03, 0);                              \
    PEXP(sa1, S##10, S##11, S##12, S##13, 1);                              \
    PEXP(sa2, S##20, S##21, S##22, S##23, 2);                              \
    PEXP(sa3, S##30, S##31, S##32, S##33, 3);                              \
    _Pragma("unroll")                                                      \
    for (int ks = 0; ks < 2; ++ks) {                                       \
        short8 ap = *(const short8*)&Pt[w][l16][ks * 32 + quad * 8];       \
        _Pragma("unroll")                                                  \
        for (int jn = 0; jn < 4; ++jn) {                                   \
            short8 bv = *(const short8*)&Vbh[(size_t)(jn * 16 + l16) * SS  \
                                             + (kb) + ks * 32 + quad * 8]; \
            accO[jn] = __builtin_amdgcn_mfma_f32_16x16x32_bf16(ap, bv, accO[jn], 0, 0, 0); \
        }                                                                  \
    }                                                                      \
} while (0)

    DECLB(bA); DECLB(bB);

    // prologue: bias chunk `phase` into set A
    LDB(bA, (phase & (NCHUNK - 1)) * KCHUNK);

    for (int c = 0; c < NCHUNK; c += 2) {
        int ka = ((c     + phase) & (NCHUNK - 1)) * KCHUNK;
        int kb_ = ((c + 1 + phase) & (NCHUNK - 1)) * KCHUNK;
        // prefetch c+1 into B, then compute c from A
        LDB(bB, kb_);
        BODY(bA, ka);
        // prefetch c+2 into A, then compute c+1 from B
        if (c + 2 < NCHUNK) {
            int kn = ((c + 2 + phase) & (NCHUNK - 1)) * KCHUNK;
            LDB(bA, kn);
        }
        BODY(bB, kb_);
    }

    // row-sum reduce across 16 l16 lanes (keys are distributed over l16)
    float rl[4];
#pragma unroll
    for (int r = 0; r < 4; ++r) {
        float s = lsum[r];
        s += __shfl_xor(s, 1, 64);
        s += __shfl_xor(s, 2, 64);
        s += __shfl_xor(s, 4, 64);
        s += __shfl_xor(s, 8, 64);
        rl[r] = 1.0f / s;
    }

    // epilogue: O = accO/lsum * G  -> bf16 Om
    int mrow = b * SS + qb + w * 16 + quad * 4;          // +r
#pragma unroll
    for (int jn = 0; jn < 4; ++jn)
#pragma unroll
        for (int r = 0; r < 4; ++r) {
            int col = h * 64 + jn * 16 + l16;
            float g = fromb(G[(size_t)(mrow + r) * DDIM + col]);
            Om[(size_t)(mrow + r) * DDIM + col] = tob(accO[jn][r] * rl[r] * g);
        }
#undef DECLB
#undef LDB
#undef PEXP
#undef BODY
}

// ---------------------------------------------------------- output GEMM -----
__global__ __launch_bounds__(256) void out_gemm(
    const unsigned short* __restrict__ Og,
    const unsigned short* __restrict__ W,
    const float* __restrict__ bo,
    float* __restrict__ out)
{
    __shared__ __align__(16) unsigned short At[64][72];
    __shared__ __align__(16) unsigned short Bt[64][72];

    int m0 = blockIdx.y * 64;
    int n0 = blockIdx.x * 64;
    int tid = threadIdx.x;
    int w = tid >> 6, lane = tid & 63;
    int quad = lane >> 4, l16 = lane & 15;
    int wm = w & 1, wn = w >> 1;

    float4v acc[2][2];
    for (int a = 0; a < 2; ++a) for (int c = 0; c < 2; ++c) acc[a][c] = (float4v)0.0f;

    for (int kc = 0; kc < DDIM; kc += 64) {
        for (int it = 0; it < 2; ++it) {
            int idx = it * 2048 + tid * 8;
            int row = idx >> 6, col = idx & 63;
            *(short8*)&At[row][col] = *(const short8*)&Og[(size_t)(m0 + row) * DDIM + kc + col];
            *(short8*)&Bt[row][col] = *(const short8*)&W[(size_t)(n0 + row) * DDIM + kc + col];
        }
        __syncthreads();
        for (int ks = 0; ks < 2; ++ks) {
            short8 a0 = *(const short8*)&At[wm * 32 + l16][ks * 32 + quad * 8];
            short8 a1 = *(const short8*)&At[wm * 32 + 16 + l16][ks * 32 + quad * 8];
            short8 b0 = *(const short8*)&Bt[wn * 32 + l16][ks * 32 + quad * 8];
            short8 b1 = *(const short8*)&Bt[wn * 32 + 16 + l16][ks * 32 + quad * 8];
            acc[0][0] = __builtin_amdgcn_mfma_f32_16x16x32_bf16(a0, b0, acc[0][0], 0, 0, 0);
            acc[0][1] = __builtin_amdgcn_mfma_f32_16x16x32_bf16(a0, b1, acc[0][1], 0, 0, 0);
            acc[1][0] = __builtin_amdgcn_mfma_f32_16x16x32_bf16(a1, b0, acc[1][0], 0, 0, 0);
            acc[1][1] = __builtin_amdgcn_mfma_f32_16x16x32_bf16(a1, b1, acc[1][1], 0, 0, 0);
        }
        __syncthreads();
    }

    for (int a = 0; a < 2; ++a) for (int c = 0; c < 2; ++c)
        for (int r = 0; r < 4; ++r) {
            int gm = m0 + wm * 32 + a * 16 + quad * 4 + r;
            int gn = n0 + wn * 32 + c * 16 + l16;
            out[(size_t)gm * DDIM + gn] = acc[a][c][r] + bo[gn];
        }
}

// ------------------------------------------------------------------ launch --
extern "C" void kernel_launch(void* const* d_in, const int* in_sizes, int n_in,
                              void* d_out, int out_size, void* d_ws, size_t ws_size,
                              hipStream_t stream)
{
    const float* x    = (const float*)d_in[0];
    const float* bias = (const float*)d_in[1];
    const float* Wq   = (const float*)d_in[2];
    const float* Wk   = (const float*)d_in[3];
    const float* Wv   = (const float*)d_in[4];
    const float* Wo   = (const float*)d_in[5];
    const float* bo   = (const float*)d_in[6];
    const float* Wg   = (const float*)d_in[7];
    const float* bg   = (const float*)d_in[8];
    float* out = (float*)d_out;

    char* ws = (char*)d_ws;
    auto alloc = [&](size_t bytes) { char* p = ws; ws += (bytes + 255) & ~(size_t)255; return p; };
    unsigned short* xb  = (unsigned short*)alloc((size_t)MM * CIN * 2);
    unsigned short* wqb = (unsigned short*)alloc((size_t)DDIM * CIN * 2);
    unsigned short* wkb = (unsigned short*)alloc((size_t)DDIM * CIN * 2);
    unsigned short* wvb = (unsigned short*)alloc((size_t)DDIM * CIN * 2);
    unsigned short* wgb = (unsigned short*)alloc((size_t)DDIM * CIN * 2);
    unsigned short* wob = (unsigned short*)alloc((size_t)DDIM * CIN * 2);
    unsigned short* Qh  = (unsigned short*)alloc((size_t)BB * HH * SS * CC * 2);
    unsigned short* Kh  = (unsigned short*)alloc((size_t)BB * HH * SS * CC * 2);
    unsigned short* Vh  = (unsigned short*)alloc((size_t)BB * HH * SS * CC * 2);
    unsigned short* Gt  = (unsigned short*)alloc((size_t)MM * DDIM * 2);
    unsigned short* Om  = (unsigned short*)alloc((size_t)MM * DDIM * 2);

    convert_all<<<3328, 256, 0, stream>>>(x, Wq, Wk, Wv, Wg, Wo,
                                          xb, wqb, wkb, wvb, wgb, wob);
    proj_gemm<<<dim3(DDIM / 64, MM / 64, 4), 256, 0, stream>>>(
        xb, wqb, wkb, wvb, wgb, bg, Qh, Kh, Vh, Gt);
    attn_kernel<<<dim3(SS / 64, BB * HH), 256, 0, stream>>>(
        Qh, Kh, Vh, bias, Gt, Om);
    out_gemm<<<dim3(DDIM / 64, MM / 64), 256, 0, stream>>>(Om, wob, bo, out);
}